// Round 9
// baseline (2907.833 us; speedup 1.0000x reference)
//
#include <hip/hip_runtime.h>

#define Bq 2
#define Lq 1024
#define Dq 128
#define Vq 5
#define RQ 128

typedef __attribute__((ext_vector_type(4))) float float4v;
typedef __attribute__((ext_vector_type(4))) int   int4v;

// ws layout (floats): [0,640) P1b  [640,1280) P2  [1280] flag(int)
#define WS_FLAG_OFF 1280

__global__ void k_flag(const int* __restrict__ x32, int* __restrict__ flag) {
    __shared__ int red[256];
    const int t = threadIdx.x;
    int acc = 0;
    for (int k = t; k < 1024; k += 256)
        acc |= x32[2 * k + 1];
    red[t] = acc;
    __syncthreads();
    for (int s = 128; s > 0; s >>= 1) {
        if (t < s) red[t] |= red[t + s];
        __syncthreads();
    }
    if (t == 0) flag[0] = red[0];
}

__device__ __forceinline__ int x_at(const int* __restrict__ x32, int f, int idx) {
    return x32[f ? idx : 2 * idx];
}

__device__ __forceinline__ float sel5(const float p[5], int v) {
    float p_ = p[4];
    p_ = (v == 3) ? p[3] : p_;
    p_ = (v == 2) ? p[2] : p_;
    p_ = (v == 1) ? p[1] : p_;
    p_ = (v == 0) ? p[0] : p_;
    return p_;
}

__global__ void k_prep(const int* __restrict__ x32,
                       const float* __restrict__ emb,
                       const float* __restrict__ W,
                       const float* __restrict__ bias,
                       float* __restrict__ ws,
                       float* __restrict__ s_out) {
    const int bid = blockIdx.x;
    const int t   = threadIdx.x;
    if (bid < Vq) {
        const int v     = bid;
        const int which = t >> 7;
        const int e     = t & 127;
        float acc = which ? 0.0f : bias[e];
        const float* wrow = W + e * (2 * Dq) + which * Dq;
        const float* erow = emb + v * Dq;
        #pragma unroll 8
        for (int d = 0; d < Dq; ++d)
            acc += erow[d] * wrow[d];
        ws[which * (Vq * Dq) + v * Dq + e] = acc;
    } else {
        const int f    = ((const int*)ws)[WS_FLAG_OFF];
        const int sb   = bid - Vq;
        const int pair = t >> 4;
        const int dgrp = t & 15;
        const int bl   = sb * 16 + pair;
        const int v    = x_at(x32, f, bl);
        const float* src = emb + v * Dq + dgrp * 8;
        float*       dst = s_out + (size_t)bl * Dq + dgrp * 8;
        float4v a = *reinterpret_cast<const float4v*>(src);
        float4v b = *reinterpret_cast<const float4v*>(src + 4);
        *reinterpret_cast<float4v*>(dst)     = a;
        *reinterpret_cast<float4v*>(dst + 4) = b;
    }
}

// ---------------------------------------------------------------------------
// R9 DIAGNOSTIC: R6 body, repeated `repeat` times in-kernel (idempotent;
// zero*pass defeats dead-store elim while keeping values bit-identical).
// NT templated. Goal: dispatch dur > fill (~690 us) so k_m's FETCH_SIZE /
// WRITE_SIZE become visible in top-5 — direct test of L2 fetch-on-write.
// ---------------------------------------------------------------------------
template<bool NT>
__global__ void __launch_bounds__(256) k_m_probe(const int* __restrict__ x32,
                                                 const float* __restrict__ ws,
                                                 float* __restrict__ m_out,
                                                 int repeat, float zero) {
    constexpr int CH = Lq / RQ;
    const int bid   = blockIdx.x;
    const int chunk = bid % CH;
    const int tmp   = bid / CH;
    const int e     = tmp % Dq;
    const int b     = tmp / Dq;
    const int t     = threadIdx.x;
    const int l1_0  = chunk * RQ;
    const int f     = ((const int*)ws)[WS_FLAG_OFF];

    float p1c[5], p2c[5];
    #pragma unroll
    for (int v = 0; v < 5; ++v) {
        p1c[v] = ws[v * Dq + e];
        p2c[v] = ws[Vq * Dq + v * Dq + e];
    }

    const int xbase = b * Lq;
    int vv[4];
    if (f) {
        int4v xv = *reinterpret_cast<const int4v*>(x32 + xbase + 4 * t);
        vv[0] = xv[0]; vv[1] = xv[1]; vv[2] = xv[2]; vv[3] = xv[3];
    } else {
        #pragma unroll
        for (int j = 0; j < 4; ++j) vv[j] = x_at(x32, 0, xbase + 4 * t + j);
    }
    float c2[4];
    #pragma unroll
    for (int j = 0; j < 4; ++j) c2[j] = sel5(p2c, vv[j]);

    __shared__ float c1s[RQ];
    if (t < RQ) {
        const int v = x_at(x32, f, xbase + l1_0 + t);
        c1s[t] = sel5(p1c, v);
    }
    __syncthreads();

    float* out_base = m_out + ((size_t)(b * Dq + e) * Lq + l1_0) * Lq + 4 * t;

    for (int pass = 0; pass < repeat; ++pass) {
        const float bump = zero * (float)pass;   // 0.0f at runtime; blocks DSE
        #pragma unroll 8
        for (int i = 0; i < RQ; ++i) {
            const float c1 = c1s[i] + bump;
            float4v o;
            #pragma unroll
            for (int j = 0; j < 4; ++j) o[j] = c1 + c2[j];
            float4v* dst = reinterpret_cast<float4v*>(out_base + (size_t)i * Lq);
            if (NT) __builtin_nontemporal_store(o, dst);
            else    *dst = o;
        }
    }
}

extern "C" void kernel_launch(void* const* d_in, const int* in_sizes, int n_in,
                              void* d_out, int out_size, void* d_ws, size_t ws_size,
                              hipStream_t stream) {
    const int*   x32  = (const int*)d_in[0];
    const float* emb  = (const float*)d_in[1];
    const float* W    = (const float*)d_in[2];
    const float* bias = (const float*)d_in[3];
    float* out   = (float*)d_out;
    float* ws    = (float*)d_ws;
    float* s_out = out;
    float* m_out = out + (size_t)Bq * Lq * Dq;

    k_flag<<<1, 256, 0, stream>>>(x32, ((int*)ws) + WS_FLAG_OFF);
    k_prep<<<Vq + (Bq * Lq / 16), 256, 0, stream>>>(x32, emb, W, bias, ws, s_out);
    // Probe A: plain L2-allocating stores, 6 passes -> dur visible in top-5.
    k_m_probe<false><<<Bq * Dq * (Lq / RQ), 256, 0, stream>>>(x32, ws, m_out, 6, 0.0f);
    // Probe B: nontemporal dense stores, 6 passes (also rewrites identical
    // values -> final output still exact).
    k_m_probe<true ><<<Bq * Dq * (Lq / RQ), 256, 0, stream>>>(x32, ws, m_out, 6, 0.0f);
}